// Round 4
// baseline (213.069 us; speedup 1.0000x reference)
//
#include <hip/hip_runtime.h>
#include <hip/hip_fp16.h>

// Volume: [B=2, X=128, Y=128, Z=128, C=1] fp32, grid: [B=2, N=2^21, 3] in [0,1].
// Output: [B, N, 1] fp32. image flat idx = b*2^21 + x*2^14 + y*2^7 + z.
//
// R1: naive fp32 gathers            180 us (FETCH 594 MB, HBM-miss bound)
// R2: fp16 volume in L2             132 us (FETCH 127 MB)
// R3: z-pair 8B windows (4 req/smp)  91 us (FETCH 112 MB) -> miss-slot bound:
//     ~3.3 cy/request = ~64 outstanding misses/CU saturated. More ILP can't
//     help; only locality can.
// R4: bin samples into 16^3-voxel cells (1024 cells = 2 batches x 8^3), then
//     sample from a 17^3 fp32 halo tile in LDS. Converts 16.8M divergent
//     global misses into streams + LDS reads. Exact fp32 coords kept in the
//     records: the reference's integral-coord -> exact-0 semantics survives.

#define TOTAL    (2 * 2097152)    // B * N
#define LOG2N    21
#define VOL      (128 * 128 * 128)
#define NVOX     (2 * VOL)
#define NCELLS   1024             // 2 batches * 8*8*8 cells of 16^3 voxels
#define CAP      5120             // bucket capacity; mean 4096, +16 sigma
#define SPT      16               // samples per thread in K1
#define TILE_N   (17 * 17 * 18)   // padded halo tile, floats

typedef unsigned int uint32;

// ---- shared device helper: direct trilinear sample from fp32 image ------
__device__ __forceinline__ float trilerp_direct(const float* __restrict__ img,
                                                float xf, float yf, float zf)
{
    const float x1f = floorf(xf), x2f = ceilf(xf);
    const float y1f = floorf(yf), y2f = ceilf(yf);
    const float z1f = floorf(zf), z2f = ceilf(zf);
    const float wx = xf - x1f, wx2 = x2f - xf;
    const float wy = yf - y1f, wy2 = y2f - yf;
    const float wz = zf - z1f, wz2 = z2f - zf;
    const int bx1 = ((int)x1f) << 14, bx2 = ((int)x2f) << 14;
    const int by1 = ((int)y1f) << 7,  by2 = ((int)y2f) << 7;
    const int iz1 = (int)z1f,         iz2 = (int)z2f;
    const float c111 = img[bx1 + by1 + iz1], c211 = img[bx2 + by1 + iz1];
    const float c121 = img[bx1 + by2 + iz1], c221 = img[bx2 + by2 + iz1];
    const float c112 = img[bx1 + by1 + iz2], c212 = img[bx2 + by1 + iz2];
    const float c122 = img[bx1 + by2 + iz2], c222 = img[bx2 + by2 + iz2];
    const float l1 = (c211 * wx + c111 * wx2) * wy2 + (c221 * wx + c121 * wx2) * wy;
    const float l2 = (c212 * wx + c112 * wx2) * wy2 + (c222 * wx + c122 * wx2) * wy;
    return l2 * wz + l1 * wz2;
}

// ---- K1: bin samples into cell buckets -----------------------------------
__global__ __launch_bounds__(256)
void ImageWarped_bin_kernel(const float* __restrict__ grid,
                            const float* __restrict__ image,
                            float* __restrict__ out,
                            uint32* __restrict__ cursor,
                            uint4* __restrict__ records)
{
    __shared__ uint32 hist[NCELLS];
    __shared__ uint32 lbase[NCELLS];
    __shared__ uint32 rank[NCELLS];

    const int tid = threadIdx.x;
    for (int b = tid; b < NCELLS; b += 256) { hist[b] = 0; rank[b] = 0; }
    __syncthreads();

    const int base = blockIdx.x * (256 * SPT);
    unsigned short bins[SPT];

    // Phase A: compute bins, LDS histogram.
    #pragma unroll
    for (int k = 0; k < SPT; ++k) {
        const int i = base + k * 256 + tid;
        const float gx = grid[3 * i + 0];
        const float gy = grid[3 * i + 1];
        const float gz = grid[3 * i + 2];
        const float xf = fminf(fmaxf(gx * 128.0f, 0.001f), 126.999f);
        const float yf = fminf(fmaxf(gy * 128.0f, 0.001f), 126.999f);
        const float zf = fminf(fmaxf(gz * 128.0f, 0.001f), 126.999f);
        const int ix1 = (int)floorf(xf);     // [0,126]
        const int iy1 = (int)floorf(yf);
        const int iz1 = (int)floorf(zf);
        const int bin = ((i >> LOG2N) << 9) | ((ix1 >> 4) << 6)
                      | ((iy1 >> 4) << 3) | (iz1 >> 4);
        bins[k] = (unsigned short)bin;
        atomicAdd(&hist[bin], 1u);           // LDS atomic
    }
    __syncthreads();

    // Phase B: reserve contiguous ranges in global buckets (returning atomics
    // only for ~1000 non-empty bins per block, executed by 256 threads).
    for (int b = tid; b < NCELLS; b += 256) {
        const uint32 c = hist[b];
        if (c) lbase[b] = atomicAdd(&cursor[b], c);
    }
    __syncthreads();

    // Phase C: re-read coords (L2-hot), scatter records.
    #pragma unroll
    for (int k = 0; k < SPT; ++k) {
        const int i = base + k * 256 + tid;
        const float gx = grid[3 * i + 0];
        const float gy = grid[3 * i + 1];
        const float gz = grid[3 * i + 2];
        const float xf = fminf(fmaxf(gx * 128.0f, 0.001f), 126.999f);
        const float yf = fminf(fmaxf(gy * 128.0f, 0.001f), 126.999f);
        const float zf = fminf(fmaxf(gz * 128.0f, 0.001f), 126.999f);
        const int bin = bins[k];
        const uint32 r = atomicAdd(&rank[bin], 1u);   // LDS atomic
        const uint32 slot = lbase[bin] + r;
        if (slot < CAP) {
            uint4 rec;
            rec.x = __float_as_uint(xf);
            rec.y = __float_as_uint(yf);
            rec.z = __float_as_uint(zf);
            rec.w = (uint32)i;
            records[(size_t)bin * CAP + slot] = rec;
        } else {
            // bucket overflow (never for uniform input): sample inline.
            const float* img = image + ((size_t)(i >> LOG2N) << LOG2N);
            out[i] = trilerp_direct(img, xf, yf, zf);
        }
    }
}

// ---- K2: per-cell LDS tile sampling --------------------------------------
__global__ __launch_bounds__(256)
void ImageWarped_sample_kernel(const float* __restrict__ image,
                               const uint32* __restrict__ cursor,
                               const uint4* __restrict__ records,
                               float* __restrict__ out)
{
    __shared__ float tile[TILE_N];   // [tx 0..16][ty 0..16][tz 0..17(pad)]

    const int cell  = blockIdx.x >> 2;
    const int sub   = blockIdx.x & 3;
    const int batch = cell >> 9;
    const int cx = (cell >> 6) & 7, cy = (cell >> 3) & 7, cz = cell & 7;
    const int tid = threadIdx.x;

    const float* __restrict__ img = image + ((size_t)batch << LOG2N);

    // Load 17^3 halo tile (z-rows of 17 floats, padded to 18).
    for (int t = tid; t < 17 * 17 * 17; t += 256) {
        const int tx = t / 289;
        const int r  = t - tx * 289;
        const int ty = r / 17;
        const int tz = r - ty * 17;
        const int x = min((cx << 4) + tx, 127);
        const int y = min((cy << 4) + ty, 127);
        const int z = min((cz << 4) + tz, 127);
        tile[(tx * 17 + ty) * 18 + tz] = img[(x << 14) | (y << 7) | z];
    }
    __syncthreads();

    const uint32 cnt = min(cursor[cell], (uint32)CAP);
    const uint32 per = (cnt + 3) >> 2;
    const uint32 begin = sub * per;
    const uint32 end   = min(begin + per, cnt);
    const uint4* __restrict__ rec = records + (size_t)cell * CAP;

    for (uint32 t = begin + tid; t < end; t += 256) {
        const uint4 q = rec[t];
        const float xf = __uint_as_float(q.x);
        const float yf = __uint_as_float(q.y);
        const float zf = __uint_as_float(q.z);

        const float x1f = floorf(xf), x2f = ceilf(xf);
        const float y1f = floorf(yf), y2f = ceilf(yf);
        const float z1f = floorf(zf), z2f = ceilf(zf);
        const float wx = xf - x1f, wx2 = x2f - xf;
        const float wy = yf - y1f, wy2 = y2f - yf;
        const float wz = zf - z1f, wz2 = z2f - zf;

        const int lx1 = ((int)x1f) & 15,     lx2 = ((int)x2f) - (cx << 4);
        const int ly1 = ((int)y1f) & 15,     ly2 = ((int)y2f) - (cy << 4);
        const int lz1 = ((int)z1f) & 15,     lz2 = ((int)z2f) - (cz << 4);

        const int r11 = (lx1 * 17 + ly1) * 18, r21 = (lx2 * 17 + ly1) * 18;
        const int r12 = (lx1 * 17 + ly2) * 18, r22 = (lx2 * 17 + ly2) * 18;

        const float c111 = tile[r11 + lz1], c211 = tile[r21 + lz1];
        const float c121 = tile[r12 + lz1], c221 = tile[r22 + lz1];
        const float c112 = tile[r11 + lz2], c212 = tile[r21 + lz2];
        const float c122 = tile[r12 + lz2], c222 = tile[r22 + lz2];

        const float l1 = (c211 * wx + c111 * wx2) * wy2
                       + (c221 * wx + c121 * wx2) * wy;
        const float l2 = (c212 * wx + c112 * wx2) * wy2
                       + (c222 * wx + c122 * wx2) * wy;
        out[q.w] = l2 * wz + l1 * wz2;
    }
}

// ---- fallback: R3 fp16 path ----------------------------------------------
__global__ __launch_bounds__(256)
void ImageWarped_cvt_fp16_kernel(const float* __restrict__ in,
                                 __half* __restrict__ out)
{
    const int i = blockIdx.x * 256 + threadIdx.x;
    const float4 v = ((const float4*)in)[i];
    union { __half2 h2[2]; uint2 u; } p;
    p.h2[0] = __floats2half2_rn(v.x, v.y);
    p.h2[1] = __floats2half2_rn(v.z, v.w);
    ((uint2*)out)[i] = p.u;
}

__global__ __launch_bounds__(256)
void ImageWarped_trilinear_h2_kernel(const __half* __restrict__ image,
                                     const float* __restrict__ grid,
                                     float* __restrict__ out)
{
    const int batch = blockIdx.x & 1;
    const int s     = (blockIdx.x >> 1) * 256 + threadIdx.x;
    const int i     = (batch << LOG2N) | s;

    const float gx = grid[3 * i + 0];
    const float gy = grid[3 * i + 1];
    const float gz = grid[3 * i + 2];
    const __half* __restrict__ img = image + ((size_t)batch << LOG2N);

    const float xf = fminf(fmaxf(gx * 128.0f, 0.001f), 126.999f);
    const float yf = fminf(fmaxf(gy * 128.0f, 0.001f), 126.999f);
    const float zf = fminf(fmaxf(gz * 128.0f, 0.001f), 126.999f);

    const float x1f = floorf(xf), x2f = ceilf(xf);
    const float y1f = floorf(yf), y2f = ceilf(yf);
    const float z1f = floorf(zf), z2f = ceilf(zf);
    const float wx = xf - x1f, wx2 = x2f - xf;
    const float wy = yf - y1f, wy2 = y2f - yf;
    const float wz = zf - z1f, wz2 = z2f - zf;

    const int bx1 = ((int)x1f) << 14, bx2 = ((int)x2f) << 14;
    const int by1 = ((int)y1f) << 7,  by2 = ((int)y2f) << 7;
    const int iz1 = (int)z1f;

    const int ze = min(iz1 & ~1, 124);
    const int sh = (iz1 - ze) << 4;

    auto zfetch = [&](int off) -> float {
        const uint2 u = *(const uint2*)(img + off + ze);
        unsigned long long w = ((unsigned long long)u.y << 32) | u.x;
        w >>= sh;
        union { unsigned int u32; __half2 h; } c;
        c.u32 = (unsigned int)w;
        const float2 f = __half22float2(c.h);
        return f.x * wz2 + f.y * wz;
    };

    const float q11 = zfetch(bx1 + by1);
    const float q21 = zfetch(bx2 + by1);
    const float q12 = zfetch(bx1 + by2);
    const float q22 = zfetch(bx2 + by2);

    out[i] = (q21 * wx + q11 * wx2) * wy2
           + (q22 * wx + q12 * wx2) * wy;
}

__global__ __launch_bounds__(256)
void ImageWarped_trilinear_f_kernel(const float* __restrict__ image,
                                    const float* __restrict__ grid,
                                    float* __restrict__ out)
{
    const int i = blockIdx.x * 256 + threadIdx.x;
    if (i >= TOTAL) return;
    const float gx = grid[3 * i + 0];
    const float gy = grid[3 * i + 1];
    const float gz = grid[3 * i + 2];
    const float* img = image + ((size_t)(i >> LOG2N) << LOG2N);
    const float xf = fminf(fmaxf(gx * 128.0f, 0.001f), 126.999f);
    const float yf = fminf(fmaxf(gy * 128.0f, 0.001f), 126.999f);
    const float zf = fminf(fmaxf(gz * 128.0f, 0.001f), 126.999f);
    out[i] = trilerp_direct(img, xf, yf, zf);
}

extern "C" void kernel_launch(void* const* d_in, const int* in_sizes, int n_in,
                              void* d_out, int out_size, void* d_ws, size_t ws_size,
                              hipStream_t stream)
{
    const float* image = (const float*)d_in[0];
    const float* grid  = (const float*)d_in[1];
    float* out = (float*)d_out;

    const size_t need = 4096 + (size_t)NCELLS * CAP * sizeof(uint4);

    if (ws_size >= need) {
        uint32* cursor  = (uint32*)d_ws;
        uint4*  records = (uint4*)((char*)d_ws + 4096);
        hipMemsetAsync(cursor, 0, NCELLS * sizeof(uint32), stream);
        ImageWarped_bin_kernel<<<TOTAL / (256 * SPT), 256, 0, stream>>>(
            grid, image, out, cursor, records);
        ImageWarped_sample_kernel<<<NCELLS * 4, 256, 0, stream>>>(
            image, cursor, records, out);
    } else if (ws_size >= (size_t)NVOX * sizeof(__half)) {
        __half* img16 = (__half*)d_ws;
        ImageWarped_cvt_fp16_kernel<<<NVOX / 4 / 256, 256, 0, stream>>>(image, img16);
        ImageWarped_trilinear_h2_kernel<<<TOTAL / 256, 256, 0, stream>>>(img16, grid, out);
    } else {
        ImageWarped_trilinear_f_kernel<<<TOTAL / 256, 256, 0, stream>>>(image, grid, out);
    }
}

// Round 5
// 174.524 us; speedup vs baseline: 1.2209x; 1.2209x over previous
//
#include <hip/hip_runtime.h>
#include <hip/hip_fp16.h>

// Volume: [B=2, X=128, Y=128, Z=128, C=1] fp32, grid: [B=2, N=2^21, 3] in [0,1].
// Output: [B, N, 1] fp32. image flat idx = b*2^21 + x*2^14 + y*2^7 + z.
//
// R1 naive fp32 gathers               180 us (FETCH 594 MB)
// R2 fp16 volume (L2-resident)        132 us (FETCH 127 MB)
// R3 z-pair 8B windows, 4 req/sample   91 us (FETCH 112 MB)
// R4 bin+LDS-tile pipeline    FAILED  148 us (scatter write-amp: out 8x,
//                                     records 2x; LDS-atomic-bound binning)
// R5 back to R3 structure + 4 samples/thread: 16 outstanding gathers/wave
//    (vs 4) to attack the ~51 us latency floor; grid as 3x float4/thread,
//    out as float4 store. fp16 volume + batch-parity XCD swizzle kept.

#define TOTAL   (2 * 2097152)   // B * N samples
#define LOG2N   21              // N = 2^21 per batch; VOL = 2^21 voxels
#define VOL     (128 * 128 * 128)
#define NVOX    (2 * VOL)
#define SPB     4               // samples per thread

// ---- pre-pass: fp32 volume -> fp16 volume in workspace -------------------
__global__ __launch_bounds__(256)
void ImageWarped_cvt_fp16_kernel(const float* __restrict__ in,
                                 __half* __restrict__ out)
{
    const int i = blockIdx.x * 256 + threadIdx.x;   // NVOX/4 threads
    const float4 v = ((const float4*)in)[i];
    union { __half2 h2[2]; uint2 u; } p;
    p.h2[0] = __floats2half2_rn(v.x, v.y);
    p.h2[1] = __floats2half2_rn(v.z, v.w);
    ((uint2*)out)[i] = p.u;
}

// ---- main: 4 samples/thread, 16 gathers in flight ------------------------
__global__ __launch_bounds__(256)
void ImageWarped_trilinear_h4_kernel(const __half* __restrict__ image,
                                     const float* __restrict__ grid,
                                     float* __restrict__ out)
{
    // Batch-parity swizzle: round-robin blockIdx%8 -> XCD means each XCD
    // sees one batch's 4.19 MiB fp16 volume (fits its 4 MiB L2).
    const int batch = blockIdx.x & 1;
    const int t     = (blockIdx.x >> 1) * 256 + threadIdx.x; // thread in batch
    const int i0    = (batch << LOG2N) | (t << 2);           // 4 consecutive samples

    // 12 coords for 4 samples = 3 aligned float4 loads (3*i0 % 4 == 0).
    const float4* __restrict__ G4 = (const float4*)grid;
    const int fb = (3 * i0) >> 2;
    const float4 ga = G4[fb + 0];
    const float4 gb = G4[fb + 1];
    const float4 gc = G4[fb + 2];

    const float cx[SPB] = { ga.x, ga.w, gb.z, gc.y };
    const float cy[SPB] = { ga.y, gb.x, gb.w, gc.z };
    const float cz[SPB] = { ga.z, gb.y, gc.x, gc.w };

    const __half* __restrict__ img = image + ((size_t)batch << LOG2N);

    float wxa[SPB], wx2a[SPB], wya[SPB], wy2a[SPB], wza[SPB], wz2a[SPB];
    int   sha[SPB];
    uint2 w11[SPB], w21[SPB], w12[SPB], w22[SPB];

    // Phase 1: addresses + ALL 16 gathers issued before any use.
    #pragma unroll
    for (int k = 0; k < SPB; ++k) {
        const float xf = fminf(fmaxf(cx[k] * 128.0f, 0.001f), 126.999f);
        const float yf = fminf(fmaxf(cy[k] * 128.0f, 0.001f), 126.999f);
        const float zf = fminf(fmaxf(cz[k] * 128.0f, 0.001f), 126.999f);

        const float x1f = floorf(xf), x2f = ceilf(xf);
        const float y1f = floorf(yf), y2f = ceilf(yf);
        const float z1f = floorf(zf), z2f = ceilf(zf);

        // Literal reference weights (integral coord -> both weights 0).
        wxa[k] = xf - x1f;  wx2a[k] = x2f - xf;
        wya[k] = yf - y1f;  wy2a[k] = y2f - yf;
        wza[k] = zf - z1f;  wz2a[k] = z2f - zf;

        const int bx1 = ((int)x1f) << 14, bx2 = ((int)x2f) << 14;
        const int by1 = ((int)y1f) << 7,  by2 = ((int)y2f) << 7;
        const int iz1 = (int)z1f;

        // 4-half window [ze, ze+3]: contains z1,z1+1; 4B-aligned; in-bounds.
        const int ze = min(iz1 & ~1, 124);
        sha[k] = (iz1 - ze) << 4;               // 0/16/32-bit shift

        const __half* p = img + ze;
        w11[k] = *(const uint2*)(p + bx1 + by1);
        w21[k] = *(const uint2*)(p + bx2 + by1);
        w12[k] = *(const uint2*)(p + bx1 + by2);
        w22[k] = *(const uint2*)(p + bx2 + by2);
    }

    // Phase 2: extract z-pairs, lerp, pack float4 result.
    float res[SPB];
    #pragma unroll
    for (int k = 0; k < SPB; ++k) {
        auto zl = [&](uint2 u) -> float {
            unsigned long long w = ((unsigned long long)u.y << 32) | u.x;
            w >>= sha[k];
            union { unsigned int u32; __half2 h; } c;
            c.u32 = (unsigned int)w;            // (c_z1, c_z2)
            const float2 f = __half22float2(c.h);
            return f.x * wz2a[k] + f.y * wza[k];   // literal z-lerp
        };
        const float q11 = zl(w11[k]);
        const float q21 = zl(w21[k]);
        const float q12 = zl(w12[k]);
        const float q22 = zl(w22[k]);
        res[k] = (q21 * wxa[k] + q11 * wx2a[k]) * wy2a[k]
               + (q22 * wxa[k] + q12 * wx2a[k]) * wya[k];
    }

    float4 o; o.x = res[0]; o.y = res[1]; o.z = res[2]; o.w = res[3];
    ((float4*)out)[i0 >> 2] = o;                 // aligned 16B store
}

// ---- fallback: direct fp32 gathers (if ws too small) ---------------------
__global__ __launch_bounds__(256)
void ImageWarped_trilinear_f_kernel(const float* __restrict__ image,
                                    const float* __restrict__ grid,
                                    float* __restrict__ out)
{
    const int i = blockIdx.x * 256 + threadIdx.x;
    if (i >= TOTAL) return;
    const float gx = grid[3 * i + 0];
    const float gy = grid[3 * i + 1];
    const float gz = grid[3 * i + 2];
    const float* __restrict__ img = image + ((size_t)(i >> LOG2N) << LOG2N);

    const float xf = fminf(fmaxf(gx * 128.0f, 0.001f), 126.999f);
    const float yf = fminf(fmaxf(gy * 128.0f, 0.001f), 126.999f);
    const float zf = fminf(fmaxf(gz * 128.0f, 0.001f), 126.999f);

    const float x1f = floorf(xf), x2f = ceilf(xf);
    const float y1f = floorf(yf), y2f = ceilf(yf);
    const float z1f = floorf(zf), z2f = ceilf(zf);
    const float wx = xf - x1f, wx2 = x2f - xf;
    const float wy = yf - y1f, wy2 = y2f - yf;
    const float wz = zf - z1f, wz2 = z2f - zf;

    const int bx1 = ((int)x1f) << 14, bx2 = ((int)x2f) << 14;
    const int by1 = ((int)y1f) << 7,  by2 = ((int)y2f) << 7;
    const int iz1 = (int)z1f,         iz2 = (int)z2f;

    const float c111 = img[bx1 + by1 + iz1], c211 = img[bx2 + by1 + iz1];
    const float c121 = img[bx1 + by2 + iz1], c221 = img[bx2 + by2 + iz1];
    const float c112 = img[bx1 + by1 + iz2], c212 = img[bx2 + by1 + iz2];
    const float c122 = img[bx1 + by2 + iz2], c222 = img[bx2 + by2 + iz2];

    const float l1 = (c211 * wx + c111 * wx2) * wy2 + (c221 * wx + c121 * wx2) * wy;
    const float l2 = (c212 * wx + c112 * wx2) * wy2 + (c222 * wx + c122 * wx2) * wy;
    out[i] = l2 * wz + l1 * wz2;
}

extern "C" void kernel_launch(void* const* d_in, const int* in_sizes, int n_in,
                              void* d_out, int out_size, void* d_ws, size_t ws_size,
                              hipStream_t stream)
{
    const float* image = (const float*)d_in[0];  // [2,128,128,128,1] fp32
    const float* grid  = (const float*)d_in[1];  // [2,2097152,3]     fp32
    float* out = (float*)d_out;                  // [2,2097152,1]     fp32

    if (ws_size >= (size_t)NVOX * sizeof(__half)) {
        __half* img16 = (__half*)d_ws;
        ImageWarped_cvt_fp16_kernel<<<NVOX / 4 / 256, 256, 0, stream>>>(image, img16);
        // TOTAL / (256 threads * 4 samples) = 4096 blocks (even: swizzle ok)
        ImageWarped_trilinear_h4_kernel<<<TOTAL / (256 * SPB), 256, 0, stream>>>(
            img16, grid, out);
    } else {
        ImageWarped_trilinear_f_kernel<<<TOTAL / 256, 256, 0, stream>>>(image, grid, out);
    }
}